// Round 1
// baseline (112.806 us; speedup 1.0000x reference)
//
#include <hip/hip_runtime.h>
#include <hip/hip_bf16.h>

typedef float f32x4 __attribute__((ext_vector_type(4)));
typedef __bf16 bf16x8 __attribute__((ext_vector_type(8)));
typedef unsigned short ushort_t;

#define SEQ 2048
#define BATCH 2
#define EMS 256
#define NHEAD 8
#define HEAD 32
#define BH (BATCH*NHEAD)

static __device__ __forceinline__ ushort_t f2bfbits(float f) {
    unsigned int u = __float_as_uint(f);
    u += 0x7fffu + ((u >> 16) & 1u);   // round-to-nearest-even
    return (ushort_t)(u >> 16);
}

static __device__ __forceinline__ bf16x8 cvt8(const float* p) {
    float4 a = *reinterpret_cast<const float4*>(p);
    float4 b = *reinterpret_cast<const float4*>(p + 4);
    union { bf16x8 v; ushort_t u[8]; } x;
    x.u[0] = f2bfbits(a.x); x.u[1] = f2bfbits(a.y);
    x.u[2] = f2bfbits(a.z); x.u[3] = f2bfbits(a.w);
    x.u[4] = f2bfbits(b.x); x.u[5] = f2bfbits(b.y);
    x.u[6] = f2bfbits(b.z); x.u[7] = f2bfbits(b.w);
    return x.v;
}

// ---------------- QKV projection ----------------
// C[r, c] = x[r, :] . W[c, :] + bias[c];  x rows r = s*B + b (em is [S,B,E] so
// flat rows ARE r).  Wave tile: 32 rows x 64 cols, K=256 in 8 steps of 32.
__global__ __launch_bounds__(256) void qkv_proj(
    const float* __restrict__ em,
    const float* __restrict__ Wq, const float* __restrict__ bq,
    const float* __restrict__ Wk, const float* __restrict__ bk,
    const float* __restrict__ Wv, const float* __restrict__ bv,
    ushort_t* __restrict__ Qb, ushort_t* __restrict__ Kb, ushort_t* __restrict__ Vb)
{
    int wid = blockIdx.x * 4 + (threadIdx.x >> 6);
    int l   = threadIdx.x & 63;
    int l15 = l & 15, lq = l >> 4;
    int rb = wid / 12, cg = wid % 12;
    int r0 = rb * 32, c0 = cg * 64;
    int sel = c0 >> 8;                       // 0=Q 1=K 2=V (uniform per wave)
    const float* W    = sel == 0 ? Wq : (sel == 1 ? Wk : Wv);
    const float* bias = sel == 0 ? bq : (sel == 1 ? bk : bv);
    ushort_t*    dst  = sel == 0 ? Qb : (sel == 1 ? Kb : Vb);
    int cb = c0 & 255;

    f32x4 acc[2][4];
    #pragma unroll
    for (int m = 0; m < 2; m++)
        #pragma unroll
        for (int n = 0; n < 4; n++) acc[m][n] = (f32x4){0.f, 0.f, 0.f, 0.f};

    #pragma unroll
    for (int kk = 0; kk < 8; kk++) {
        int k0 = kk * 32;
        bf16x8 af[2];
        #pragma unroll
        for (int m = 0; m < 2; m++)
            af[m] = cvt8(em + (size_t)(r0 + m * 16 + l15) * EMS + k0 + lq * 8);
        bf16x8 bfm[4];
        #pragma unroll
        for (int n = 0; n < 4; n++)
            bfm[n] = cvt8(W + (size_t)(cb + n * 16 + l15) * EMS + k0 + lq * 8);
        #pragma unroll
        for (int m = 0; m < 2; m++)
            #pragma unroll
            for (int n = 0; n < 4; n++)
                acc[m][n] = __builtin_amdgcn_mfma_f32_16x16x32_bf16(af[m], bfm[n], acc[m][n], 0, 0, 0);
    }

    float scale = (sel == 0) ? 0.17677669529663687f : 1.0f;  // 1/sqrt(32) folded into Q
    #pragma unroll
    for (int m = 0; m < 2; m++) {
        #pragma unroll
        for (int n = 0; n < 4; n++) {
            int c = cb + n * 16 + l15;       // 0..255 within this projection
            float bv_ = bias[c];
            int h = c >> 5, d = c & 31;
            #pragma unroll
            for (int r = 0; r < 4; r++) {
                int row = r0 + m * 16 + lq * 4 + r;   // C/D: row=(l>>4)*4+reg, col=l&15
                int s = row >> 1, b = row & 1;
                float v = (acc[m][n][r] + bv_) * scale;
                dst[((size_t)(b * NHEAD + h) * SEQ + s) * HEAD + d] = f2bfbits(v);
            }
        }
    }
}

// ---------------- V transpose: [bh][s][d] -> [bh][d][s] ----------------
__global__ __launch_bounds__(256) void vtrans(const ushort_t* __restrict__ Vb,
                                              ushort_t* __restrict__ Vt)
{
    __shared__ ushort_t t[HEAD][65];
    int g = blockIdx.x;
    int bh = g & 15, st = g >> 4;
    int s0 = st * 64;
    int tid = threadIdx.x;
    #pragma unroll
    for (int i = 0; i < 8; i++) {
        int idx = i * 256 + tid;
        int sl = idx >> 5, d = idx & 31;
        t[d][sl] = Vb[((size_t)bh * SEQ + s0 + sl) * HEAD + d];
    }
    __syncthreads();
    #pragma unroll
    for (int i = 0; i < 8; i++) {
        int idx = i * 256 + tid;
        int d = idx >> 6, sl = idx & 63;
        Vt[((size_t)bh * HEAD + d) * SEQ + s0 + sl] = t[d][sl];
    }
}

// ---------------- Flash attention ----------------
// 1 wave handles (bh, 16 q-rows).  Block = 4 waves = 4 heads sharing (b, qt)
// so mask tiles are L1-shared.
__global__ __launch_bounds__(256) void attn(
    const ushort_t* __restrict__ Qb, const ushort_t* __restrict__ Kb,
    const ushort_t* __restrict__ Vt, const float* __restrict__ mask,
    float* __restrict__ out)
{
    int g  = blockIdx.x;
    int qt = g >> 2;
    int b  = (g >> 1) & 1;
    int hg = g & 1;
    int w  = threadIdx.x >> 6;
    int l  = threadIdx.x & 63;
    int h  = hg * 4 + w;
    int bh = b * NHEAD + h;
    int qs0 = qt * 16;
    int l15 = l & 15, lq = l >> 4;

    __shared__ ushort_t plds[4][16][40];   // pad to 40 (80B rows): 16B aligned, <=2-way banks
    ushort_t (*P)[40] = plds[w];

    bf16x8 qf = *reinterpret_cast<const bf16x8*>(
        Qb + ((size_t)bh * SEQ + qs0 + l15) * HEAD + lq * 8);

    f32x4 acc0 = {0.f, 0.f, 0.f, 0.f}, acc1 = {0.f, 0.f, 0.f, 0.f};
    float mrun[4], lsum[4];
    #pragma unroll
    for (int r = 0; r < 4; r++) { mrun[r] = -1e30f; lsum[r] = 0.f; }

    const float*   mbase  = mask + (size_t)b * SEQ * SEQ + (size_t)qs0 * SEQ;
    const ushort_t* kbase  = Kb + (size_t)bh * SEQ * HEAD;
    const ushort_t* vtbase = Vt + (size_t)bh * HEAD * SEQ;

    for (int kt = 0; kt < SEQ / 32; kt++) {
        int ks0 = kt * 32;
        bf16x8 kf0 = *reinterpret_cast<const bf16x8*>(kbase + (size_t)(ks0 + l15) * HEAD + lq * 8);
        bf16x8 kf1 = *reinterpret_cast<const bf16x8*>(kbase + (size_t)(ks0 + 16 + l15) * HEAD + lq * 8);
        f32x4 z = {0.f, 0.f, 0.f, 0.f};
        f32x4 s0 = __builtin_amdgcn_mfma_f32_16x16x32_bf16(qf, kf0, z, 0, 0, 0);
        f32x4 s1 = __builtin_amdgcn_mfma_f32_16x16x32_bf16(qf, kf1, z, 0, 0, 0);

        float sv0[4], sv1[4];
        #pragma unroll
        for (int r = 0; r < 4; r++) {
            const float* mrow = mbase + (size_t)(lq * 4 + r) * SEQ + ks0 + l15;
            sv0[r] = s0[r] + mrow[0];
            sv1[r] = s1[r] + mrow[16];
        }

        float p0[4], p1[4];
        #pragma unroll
        for (int r = 0; r < 4; r++) {
            float t = fmaxf(sv0[r], sv1[r]);
            t = fmaxf(t, __shfl_xor(t, 1));
            t = fmaxf(t, __shfl_xor(t, 2));
            t = fmaxf(t, __shfl_xor(t, 4));
            t = fmaxf(t, __shfl_xor(t, 8));
            float nm = fmaxf(mrun[r], t);
            float sc = __expf(mrun[r] - nm);
            mrun[r] = nm;
            p0[r] = __expf(sv0[r] - nm);
            p1[r] = __expf(sv1[r] - nm);
            float rs = p0[r] + p1[r];
            rs += __shfl_xor(rs, 1);
            rs += __shfl_xor(rs, 2);
            rs += __shfl_xor(rs, 4);
            rs += __shfl_xor(rs, 8);
            lsum[r] = lsum[r] * sc + rs;
            acc0[r] *= sc;
            acc1[r] *= sc;
            P[lq * 4 + r][l15]      = f2bfbits(p0[r]);
            P[lq * 4 + r][16 + l15] = f2bfbits(p1[r]);
        }

        asm volatile("s_waitcnt lgkmcnt(0)" ::: "memory");  // intra-wave LDS transpose fence

        bf16x8 pf  = *reinterpret_cast<const bf16x8*>(&P[l15][lq * 8]);
        bf16x8 vf0 = *reinterpret_cast<const bf16x8*>(vtbase + (size_t)l15 * SEQ + ks0 + lq * 8);
        bf16x8 vf1 = *reinterpret_cast<const bf16x8*>(vtbase + (size_t)(16 + l15) * SEQ + ks0 + lq * 8);
        acc0 = __builtin_amdgcn_mfma_f32_16x16x32_bf16(pf, vf0, acc0, 0, 0, 0);
        acc1 = __builtin_amdgcn_mfma_f32_16x16x32_bf16(pf, vf1, acc1, 0, 0, 0);
    }

    #pragma unroll
    for (int r = 0; r < 4; r++) {
        int q = qs0 + lq * 4 + r;
        float inv = 1.0f / lsum[r];
        size_t o0 = ((size_t)q * BATCH + b) * EMS + h * HEAD;
        out[o0 + l15]      = acc0[r] * inv;
        out[o0 + 16 + l15] = acc1[r] * inv;
    }
}

extern "C" void kernel_launch(void* const* d_in, const int* in_sizes, int n_in,
                              void* d_out, int out_size, void* d_ws, size_t ws_size,
                              hipStream_t stream) {
    const float* em  = (const float*)d_in[0];
    const float* mask = (const float*)d_in[1];
    const float* Wq  = (const float*)d_in[2];
    const float* bq  = (const float*)d_in[3];
    const float* Wk  = (const float*)d_in[4];
    const float* bk  = (const float*)d_in[5];
    const float* Wv  = (const float*)d_in[6];
    const float* bv  = (const float*)d_in[7];
    float* out = (float*)d_out;

    ushort_t* Qb = (ushort_t*)d_ws;                       // [BH][S][D] bf16, 2MB
    ushort_t* Kb = Qb + (size_t)BH * SEQ * HEAD;          // 2MB
    ushort_t* Vb = Kb + (size_t)BH * SEQ * HEAD;          // 2MB
    ushort_t* Vt = Vb + (size_t)BH * SEQ * HEAD;          // [BH][D][S] bf16, 2MB

    qkv_proj<<<dim3(384), dim3(256), 0, stream>>>(em, Wq, bq, Wk, bk, Wv, bv, Qb, Kb, Vb);
    vtrans<<<dim3(512), dim3(256), 0, stream>>>(Vb, Vt);
    attn<<<dim3(512), dim3(256), 0, stream>>>(Qb, Kb, Vt, mask, out);
}

// Round 2
// 104.497 us; speedup vs baseline: 1.0795x; 1.0795x over previous
//
#include <hip/hip_runtime.h>
#include <hip/hip_bf16.h>

typedef float f32x4 __attribute__((ext_vector_type(4)));
typedef __bf16 bf16x8 __attribute__((ext_vector_type(8)));
typedef unsigned short ushort_t;

#define SEQ 2048
#define BATCH 2
#define EMS 256
#define NHEAD 8
#define HEAD 32
#define BH (BATCH*NHEAD)

static __device__ __forceinline__ ushort_t f2bfbits(float f) {
    unsigned int u = __float_as_uint(f);
    u += 0x7fffu + ((u >> 16) & 1u);   // round-to-nearest-even
    return (ushort_t)(u >> 16);
}

static __device__ __forceinline__ bf16x8 cvt8(const float* p) {
    float4 a = *reinterpret_cast<const float4*>(p);
    float4 b = *reinterpret_cast<const float4*>(p + 4);
    union { bf16x8 v; ushort_t u[8]; } x;
    x.u[0] = f2bfbits(a.x); x.u[1] = f2bfbits(a.y);
    x.u[2] = f2bfbits(a.z); x.u[3] = f2bfbits(a.w);
    x.u[4] = f2bfbits(b.x); x.u[5] = f2bfbits(b.y);
    x.u[6] = f2bfbits(b.z); x.u[7] = f2bfbits(b.w);
    return x.v;
}

// ---------------- QKV projection ----------------
__global__ __launch_bounds__(256) void qkv_proj(
    const float* __restrict__ em,
    const float* __restrict__ Wq, const float* __restrict__ bq,
    const float* __restrict__ Wk, const float* __restrict__ bk,
    const float* __restrict__ Wv, const float* __restrict__ bv,
    ushort_t* __restrict__ Qb, ushort_t* __restrict__ Kb, ushort_t* __restrict__ Vb)
{
    int wid = blockIdx.x * 4 + (threadIdx.x >> 6);
    int l   = threadIdx.x & 63;
    int l15 = l & 15, lq = l >> 4;
    int rb = wid / 12, cg = wid % 12;
    int r0 = rb * 32, c0 = cg * 64;
    int sel = c0 >> 8;                       // 0=Q 1=K 2=V (uniform per wave)
    const float* W    = sel == 0 ? Wq : (sel == 1 ? Wk : Wv);
    const float* bias = sel == 0 ? bq : (sel == 1 ? bk : bv);
    ushort_t*    dst  = sel == 0 ? Qb : (sel == 1 ? Kb : Vb);
    int cb = c0 & 255;

    f32x4 acc[2][4];
    #pragma unroll
    for (int m = 0; m < 2; m++)
        #pragma unroll
        for (int n = 0; n < 4; n++) acc[m][n] = (f32x4){0.f, 0.f, 0.f, 0.f};

    #pragma unroll
    for (int kk = 0; kk < 8; kk++) {
        int k0 = kk * 32;
        bf16x8 af[2];
        #pragma unroll
        for (int m = 0; m < 2; m++)
            af[m] = cvt8(em + (size_t)(r0 + m * 16 + l15) * EMS + k0 + lq * 8);
        bf16x8 bfm[4];
        #pragma unroll
        for (int n = 0; n < 4; n++)
            bfm[n] = cvt8(W + (size_t)(cb + n * 16 + l15) * EMS + k0 + lq * 8);
        #pragma unroll
        for (int m = 0; m < 2; m++)
            #pragma unroll
            for (int n = 0; n < 4; n++)
                acc[m][n] = __builtin_amdgcn_mfma_f32_16x16x32_bf16(af[m], bfm[n], acc[m][n], 0, 0, 0);
    }

    float scale = (sel == 0) ? 0.17677669529663687f : 1.0f;  // 1/sqrt(32) folded into Q
    #pragma unroll
    for (int m = 0; m < 2; m++) {
        #pragma unroll
        for (int n = 0; n < 4; n++) {
            int c = cb + n * 16 + l15;
            float bv_ = bias[c];
            int h = c >> 5, d = c & 31;
            #pragma unroll
            for (int r = 0; r < 4; r++) {
                int row = r0 + m * 16 + lq * 4 + r;   // C/D: row=(l>>4)*4+reg, col=l&15
                int s = row >> 1, b = row & 1;
                float v = (acc[m][n][r] + bv_) * scale;
                dst[((size_t)(b * NHEAD + h) * SEQ + s) * HEAD + d] = f2bfbits(v);
            }
        }
    }
}

// ---------------- V transpose: [bh][s][d] -> [bh][d][s] ----------------
__global__ __launch_bounds__(256) void vtrans(const ushort_t* __restrict__ Vb,
                                              ushort_t* __restrict__ Vt)
{
    __shared__ ushort_t t[HEAD][65];
    int g = blockIdx.x;
    int bh = g & 15, st = g >> 4;
    int s0 = st * 64;
    int tid = threadIdx.x;
    #pragma unroll
    for (int i = 0; i < 8; i++) {
        int idx = i * 256 + tid;
        int sl = idx >> 5, d = idx & 31;
        t[d][sl] = Vb[((size_t)bh * SEQ + s0 + sl) * HEAD + d];
    }
    __syncthreads();
    #pragma unroll
    for (int i = 0; i < 8; i++) {
        int idx = i * 256 + tid;
        int d = idx >> 6, sl = idx & 63;
        Vt[((size_t)bh * HEAD + d) * SEQ + s0 + sl] = t[d][sl];
    }
}

// ---------------- Flash attention, swapped QK^T ----------------
// 1 wave = (bh, 16 q-rows).  S^T = mfma(K, Q): lane owns q = l&15, holds 8
// scores in-register -> row reduce = 7 fmax + 2 shfl_xor (vs 32 shuffles).
// K/V/mask loads software-pipelined one k-tile ahead.
__global__ __launch_bounds__(256) void attn(
    const ushort_t* __restrict__ Qb, const ushort_t* __restrict__ Kb,
    const ushort_t* __restrict__ Vt, const float* __restrict__ mask,
    float* __restrict__ out)
{
    int g  = blockIdx.x;
    int qt = g >> 2;
    int b  = (g >> 1) & 1;
    int hg = g & 1;
    int w  = threadIdx.x >> 6;
    int l  = threadIdx.x & 63;
    int h  = hg * 4 + w;
    int bh = b * NHEAD + h;
    int qs0 = qt * 16;
    int l15 = l & 15, lq = l >> 4;

    __shared__ ushort_t plds[4][16][40];   // 80B rows: 16B aligned, ~2-way banks
    ushort_t (*P)[40] = plds[w];

    // Q as B-operand: col=q=l15, khead=lq*8..
    bf16x8 qf = *reinterpret_cast<const bf16x8*>(
        Qb + ((size_t)bh * SEQ + qs0 + l15) * HEAD + lq * 8);

    f32x4 acc0 = {0.f, 0.f, 0.f, 0.f}, acc1 = {0.f, 0.f, 0.f, 0.f};
    float mrun = -1e30f, lsum = 0.f;       // stats for q = l15 (replicated over lq)

    const float*    mrow  = mask + (size_t)b * SEQ * SEQ + (size_t)(qs0 + l15) * SEQ;
    const ushort_t* kptr  = Kb + ((size_t)bh * SEQ + l15) * HEAD + lq * 8;
    const ushort_t* vptr  = Vt + ((size_t)bh * HEAD + l15) * SEQ + lq * 8;

    // prefetch tile 0
    bf16x8 kc0 = *(const bf16x8*)(kptr);
    bf16x8 kc1 = *(const bf16x8*)(kptr + 16 * HEAD);
    float4 mc0 = *(const float4*)(mrow + lq * 4);
    float4 mc1 = *(const float4*)(mrow + 16 + lq * 4);
    bf16x8 vc0 = *(const bf16x8*)(vptr);
    bf16x8 vc1 = *(const bf16x8*)(vptr + 16 * SEQ);

    #pragma unroll 2
    for (int kt = 0; kt < SEQ / 32; kt++) {
        int ks1 = (kt + 1 < SEQ / 32) ? (kt + 1) * 32 : 0;   // wrap: load discarded
        f32x4 z = {0.f, 0.f, 0.f, 0.f};
        // S^T[k_seq][q]: col=l15=q, row=lq*4+r=k_seq (first 16), +16 for second
        f32x4 s0 = __builtin_amdgcn_mfma_f32_16x16x32_bf16(kc0, qf, z, 0, 0, 0);
        f32x4 s1 = __builtin_amdgcn_mfma_f32_16x16x32_bf16(kc1, qf, z, 0, 0, 0);

        // prefetch next tile while softmax runs
        bf16x8 kn0 = *(const bf16x8*)(kptr + (size_t)ks1 * HEAD);
        bf16x8 kn1 = *(const bf16x8*)(kptr + (size_t)(ks1 + 16) * HEAD);
        float4 mn0 = *(const float4*)(mrow + ks1 + lq * 4);
        float4 mn1 = *(const float4*)(mrow + ks1 + 16 + lq * 4);
        bf16x8 vn0 = *(const bf16x8*)(vptr + ks1);
        bf16x8 vn1 = *(const bf16x8*)(vptr + ks1 + 16 * SEQ);

        float sv[8];
        sv[0] = s0[0] + mc0.x; sv[1] = s0[1] + mc0.y;
        sv[2] = s0[2] + mc0.z; sv[3] = s0[3] + mc0.w;
        sv[4] = s1[0] + mc1.x; sv[5] = s1[1] + mc1.y;
        sv[6] = s1[2] + mc1.z; sv[7] = s1[3] + mc1.w;

        float pmax = fmaxf(fmaxf(fmaxf(sv[0], sv[1]), fmaxf(sv[2], sv[3])),
                           fmaxf(fmaxf(sv[4], sv[5]), fmaxf(sv[6], sv[7])));
        pmax = fmaxf(pmax, __shfl_xor(pmax, 16));
        pmax = fmaxf(pmax, __shfl_xor(pmax, 32));
        float nm = fmaxf(mrun, pmax);
        if (__any(nm > mrun)) {            // rescale only when a row max increased
            float sc = __expf(mrun - nm);
            mrun = nm;
            lsum *= sc;
            #pragma unroll
            for (int r = 0; r < 4; r++) {  // acc rows are q=lq*4+r; sc lives at l15=q
                float scr = __shfl(sc, (l & 48) | (lq * 4 + r));
                acc0[r] *= scr;
                acc1[r] *= scr;
            }
        }

        float rs = 0.f;
        ushort_t pb[8];
        #pragma unroll
        for (int j = 0; j < 8; j++) {
            float e = __expf(sv[j] - mrun);
            rs += e;
            pb[j] = f2bfbits(e);
        }
        rs += __shfl_xor(rs, 16);
        rs += __shfl_xor(rs, 32);
        lsum += rs;

        // P[q=l15][k]: k = lq*4+{0..3} and 16+lq*4+{0..3}, packed as b32 writes
        unsigned* prow = reinterpret_cast<unsigned*>(&P[l15][0]);
        prow[(lq * 4) >> 1]        = (unsigned)pb[0] | ((unsigned)pb[1] << 16);
        prow[(lq * 4 + 2) >> 1]    = (unsigned)pb[2] | ((unsigned)pb[3] << 16);
        prow[(16 + lq * 4) >> 1]   = (unsigned)pb[4] | ((unsigned)pb[5] << 16);
        prow[(16 + lq * 4 + 2) >> 1] = (unsigned)pb[6] | ((unsigned)pb[7] << 16);

        asm volatile("s_waitcnt lgkmcnt(0)" ::: "memory");
        __builtin_amdgcn_sched_barrier(0);

        bf16x8 pf = *reinterpret_cast<const bf16x8*>(&P[l15][lq * 8]);
        acc0 = __builtin_amdgcn_mfma_f32_16x16x32_bf16(pf, vc0, acc0, 0, 0, 0);
        acc1 = __builtin_amdgcn_mfma_f32_16x16x32_bf16(pf, vc1, acc1, 0, 0, 0);

        kc0 = kn0; kc1 = kn1; mc0 = mn0; mc1 = mn1; vc0 = vn0; vc1 = vn1;
    }

    float linv = 1.0f / lsum;              // valid in lanes keyed by l15=q
    #pragma unroll
    for (int r = 0; r < 4; r++) {
        int q = qs0 + lq * 4 + r;
        float inv = __shfl(linv, (l & 48) | (lq * 4 + r));
        size_t o0 = ((size_t)q * BATCH + b) * EMS + h * HEAD;
        out[o0 + l15]      = acc0[r] * inv;
        out[o0 + 16 + l15] = acc1[r] * inv;
    }
}

extern "C" void kernel_launch(void* const* d_in, const int* in_sizes, int n_in,
                              void* d_out, int out_size, void* d_ws, size_t ws_size,
                              hipStream_t stream) {
    const float* em  = (const float*)d_in[0];
    const float* mask = (const float*)d_in[1];
    const float* Wq  = (const float*)d_in[2];
    const float* bq  = (const float*)d_in[3];
    const float* Wk  = (const float*)d_in[4];
    const float* bk  = (const float*)d_in[5];
    const float* Wv  = (const float*)d_in[6];
    const float* bv  = (const float*)d_in[7];
    float* out = (float*)d_out;

    ushort_t* Qb = (ushort_t*)d_ws;                       // [BH][S][D] bf16, 2MB
    ushort_t* Kb = Qb + (size_t)BH * SEQ * HEAD;          // 2MB
    ushort_t* Vb = Kb + (size_t)BH * SEQ * HEAD;          // 2MB
    ushort_t* Vt = Vb + (size_t)BH * SEQ * HEAD;          // [BH][D][S] bf16, 2MB

    qkv_proj<<<dim3(384), dim3(256), 0, stream>>>(em, Wq, bq, Wk, bk, Wv, bv, Qb, Kb, Vb);
    vtrans<<<dim3(512), dim3(256), 0, stream>>>(Vb, Vt);
    attn<<<dim3(512), dim3(256), 0, stream>>>(Qb, Kb, Vt, mask, out);
}